// Round 12
// baseline (169.103 us; speedup 1.0000x reference)
//
#include <hip/hip_runtime.h>
#include <math.h>

#define TT 128
#define IN_CH 32
#define NPATH 256
#define SIGCH 7380
#define K1 29520
#define N1 512
#define N2 256
#define BK 24

// ---------------- Kernel 1: conv + time-augment + depth-4 signature ----------------
// 1024-thread block per path, 4 groups of 243 threads. Chen time-split:
// group g scans quarter [32g, 32g+32) independently; tree-merge via LDS.
// Output ROW-MAJOR sig[p][7380]: coalesced stores.
__global__ __launch_bounds__(1024) void sig_kernel(const float* __restrict__ x,
        const float* __restrict__ cw, const float* __restrict__ cb,
        float* __restrict__ sig /*[256][7380] row-major*/) {
    __shared__ float incT[9][132];
    __shared__ float sb[2][7392];
    const int p = blockIdx.x;
    const int b = p >> 2, oc = p & 3;
    const int tid = threadIdx.x;

    const float4 wv = *(const float4*)(cw + oc * 4);
    const float bias = cb[oc];
    const float* xb = x + (long)b * TT * IN_CH;

    {   // staging: one (t,ch) per thread
        const int t = tid >> 3, ch = tid & 7;
        const float4 xa = *(const float4*)(xb + t * IN_CH + ch * 4);
        float v = xa.x * wv.x + xa.y * wv.y + xa.z * wv.z + xa.w * wv.w + bias;
        if (t > 0) {
            const float4 xm = *(const float4*)(xb + (t - 1) * IN_CH + ch * 4);
            v -= xm.x * wv.x + xm.y * wv.y + xm.z * wv.z + xm.w * wv.w + bias;
        }
        incT[1 + ch][t] = v;
        if (tid < TT) incT[0][tid] = tid ? (1.f / 127.f) : 0.f;
    }
    __syncthreads();

    const int g = tid >> 8;              // group 0..3
    const int gtid = tid & 255;
    const bool act = gtid < 243;
    const int base3 = 3 * gtid;
    const int i1 = base3 / 81;
    const int i2 = (base3 / 9) % 9;
    const int i30 = base3 % 9;           // {0,3,6}
    const int lane = tid & 63;
    const int grow = min(lane, 8);

    float S4[3][9] = {};
    float s3[3] = {0.f, 0.f, 0.f};
    float s2 = 0.f, s1 = 0.f;

#define LD(R, T4) (*(const float4*)&incT[(R)][(T4)])
#define RL(XV, C) __int_as_float(__builtin_amdgcn_readlane(__float_as_int(XV), (C)))
#define STEP(GJ, E1, E2, F0, F1, F2) do { \
    const float t12 = (E1) * (E2); \
    const float s1d2 = s1 * (E2); \
    const float Ak = t12 * (1.f / 24.f) + s1d2 * (1.f / 6.f) + s2 * 0.5f; \
    const float Bk = t12 * (1.f / 6.f) + s1d2 * 0.5f + s2; \
    const float K0 = (F0) * Ak + s3[0]; \
    const float K1v = (F1) * Ak + s3[1]; \
    const float K2v = (F2) * Ak + s3[2]; \
    _Pragma("unroll") \
    for (int c = 0; c < 9; ++c) { \
        const float Ac = RL(GJ, c); \
        S4[0][c] += K0 * Ac; S4[1][c] += K1v * Ac; S4[2][c] += K2v * Ac; \
    } \
    s3[0] += Bk * (F0); s3[1] += Bk * (F1); s3[2] += Bk * (F2); \
    s2 += (E2) * (0.5f * (E1) + s1); \
    s1 += (E1); \
} while (0)

    if (act) {
        const int t0 = g * 32;
        float4 gA = LD(grow, t0), e1v = LD(i1, t0), e2v = LD(i2, t0);
        float4 f0v = LD(i30, t0), f1v = LD(i30 + 1, t0), f2v = LD(i30 + 2, t0);
        for (int j = 0; j < 8; ++j) {
            const int t4 = t0 + (((j + 1) & 7) << 2);     // last prefetch dummy
            const float4 ngA = LD(grow, t4);
            const float4 ne1 = LD(i1, t4), ne2 = LD(i2, t4);
            const float4 nf0 = LD(i30, t4), nf1 = LD(i30 + 1, t4), nf2 = LD(i30 + 2, t4);
            STEP(gA.x, e1v.x, e2v.x, f0v.x, f1v.x, f2v.x);
            STEP(gA.y, e1v.y, e2v.y, f0v.y, f1v.y, f2v.y);
            STEP(gA.z, e1v.z, e2v.z, f0v.z, f1v.z, f2v.z);
            STEP(gA.w, e1v.w, e2v.w, f0v.w, f1v.w, f2v.w);
            gA = ngA; e1v = ne1; e2v = ne2; f0v = nf0; f1v = nf1; f2v = nf2;
        }
    }
#undef STEP
#undef RL
#undef LD

    // ---- Chen tree-merge: (0,1)->0, (2,3)->2, then (0,2)->0 ----
#define WRITE_SIG(D) do { \
    float* d_ = (D); \
    if (i2 == 0 && i30 == 0) d_[i1] = s1; \
    if (i30 == 0) d_[9 + i1 * 9 + i2] = s2; \
    d_[90 + base3] = s3[0]; d_[90 + base3 + 1] = s3[1]; d_[90 + base3 + 2] = s3[2]; \
    _Pragma("unroll") \
    for (int q = 0; q < 3; ++q) \
        _Pragma("unroll") \
        for (int c = 0; c < 9; ++c) d_[819 + (base3 + q) * 9 + c] = S4[q][c]; \
} while (0)

#define MERGE_SIG(S) do { \
    const float* sB_ = (S); \
    float S1B[9]; \
    _Pragma("unroll") \
    for (int c = 0; c < 9; ++c) S1B[c] = sB_[c]; \
    _Pragma("unroll") \
    for (int q = 0; q < 3; ++q) { \
        const int i3q = i30 + q; \
        _Pragma("unroll") \
        for (int c = 0; c < 9; ++c) { \
            S4[q][c] += s3[q] * S1B[c] \
                      + s2 * sB_[9 + i3q * 9 + c] \
                      + s1 * sB_[90 + i2 * 81 + i3q * 9 + c] \
                      + sB_[819 + (base3 + q) * 9 + c]; \
        } \
    } \
    _Pragma("unroll") \
    for (int q = 0; q < 3; ++q) \
        s3[q] += s2 * S1B[i30 + q] + s1 * sB_[9 + i2 * 9 + (i30 + q)] + sB_[90 + base3 + q]; \
    s2 += s1 * S1B[i2] + sB_[9 + i1 * 9 + i2]; \
    s1 += S1B[i1]; \
} while (0)

    if (act && (g == 1 || g == 3)) WRITE_SIG(sb[g >> 1]);
    __syncthreads();
    if (act && g == 0) MERGE_SIG(sb[0]);
    if (act && g == 2) MERGE_SIG(sb[1]);
    __syncthreads();
    if (act && g == 2) WRITE_SIG(sb[0]);
    __syncthreads();
    if (act && g == 0) {
        MERGE_SIG(sb[0]);
        float* sp = sig + (long)p * SIGCH;      // row-major, coalesced
        if (i2 == 0 && i30 == 0) sp[i1] = s1;
        if (i30 == 0) sp[9 + base3 / 9] = s2;
        sp[90 + base3 + 0] = s3[0];
        sp[90 + base3 + 1] = s3[1];
        sp[90 + base3 + 2] = s3[2];
#pragma unroll
        for (int q = 0; q < 3; q++)
#pragma unroll
            for (int l = 0; l < 9; l++)
                sp[819 + (base3 + q) * 9 + l] = S4[q][l];
    }
#undef WRITE_SIG
#undef MERGE_SIG
}

// ---------------- Kernel 2: GEMM1 partials (pure-DS hot loop) ----------------
// Block = 64 rows x 256 cols, 4 waves; wave = 16 rows x 256 cols (4 cols/lane).
// Per-tile (BK=24): z re-transposed into LDS zt[k][64]; per k a wave reads its
// 16 z-rows as 4 UNIFORM-ADDRESS ds_read_b128 (broadcast, conflict-free) and
// w as 1 per-lane ds_read_b128 -> 5 LDS issues per 128 VALU-cyc. NO s_load in
// the hot loop: lgkmcnt is pure-DS (in-order, fine counts); staging loads are
// global->VGPR (vmcnt) issued at tile start, ds_write just before the barrier.
// Grid = 2 n-halves x 246 k-chunks = 492 blocks (~2/CU); LDS 60KB.
__global__ __launch_bounds__(256) void gemm1_kernel(const float* __restrict__ zsig,
        const float* __restrict__ w0, float* __restrict__ part, int KCH) {
    __shared__ float wt[2][BK][256];
    __shared__ float zt[2][BK][64];
    const int nh = blockIdx.x;            // 0/1
    const int kc = blockIdx.y;
    const int n0 = nh * 256, k0 = kc * KCH;
    const int tid = threadIdx.x;
    const int lane = tid & 63;
    const int wvid = __builtin_amdgcn_readfirstlane(tid >> 6);  // 0..3
    const int r0 = wvid * 16;
    const int c4 = lane * 4;
    const int kb6 = wvid * 6;             // this wave's z k-rows [kb6, kb6+6)

    float4 wreg[6];
    float zreg[6];

#define STAGE_LOAD(T) do { \
    const int kk_ = k0 + (T) * BK; \
    _Pragma("unroll") \
    for (int i = 0; i < 6; ++i) { \
        const int slot = tid + i * 256; \
        wreg[i] = *(const float4*)(w0 + (long)(kk_ + (slot >> 6)) * N1 + n0 + (slot & 63) * 4); \
    } \
    _Pragma("unroll") \
    for (int j = 0; j < 6; ++j) \
        zreg[j] = zsig[(long)lane * K1 + kk_ + kb6 + j]; \
} while (0)

#define STAGE_WRITE(B) do { \
    _Pragma("unroll") \
    for (int i = 0; i < 6; ++i) { \
        const int slot = tid + i * 256; \
        *(float4*)&wt[B][slot >> 6][(slot & 63) * 4] = wreg[i]; \
    } \
    _Pragma("unroll") \
    for (int j = 0; j < 6; ++j) \
        zt[B][kb6 + j][lane] = zreg[j]; \
} while (0)

    float acc[16][4] = {};
    const int NT = KCH / BK;

    STAGE_LOAD(0);
    STAGE_WRITE(0);
    __syncthreads();

    int cur = 0;
    for (int t = 0; t < NT; ++t) {
        if (t + 1 < NT) STAGE_LOAD(t + 1);          // vmcnt domain, hides under compute
#pragma unroll
        for (int k = 0; k < BK; ++k) {
            const float4 za = *(const float4*)&zt[cur][k][r0];       // uniform
            const float4 zb = *(const float4*)&zt[cur][k][r0 + 4];   // uniform
            const float4 zc = *(const float4*)&zt[cur][k][r0 + 8];   // uniform
            const float4 zd = *(const float4*)&zt[cur][k][r0 + 12];  // uniform
            const float4 wf = *(const float4*)&wt[cur][k][c4];       // per-lane
#define ROW(R, ZV) \
            acc[R][0] += (ZV) * wf.x; acc[R][1] += (ZV) * wf.y; \
            acc[R][2] += (ZV) * wf.z; acc[R][3] += (ZV) * wf.w;
            ROW(0, za.x) ROW(1, za.y) ROW(2, za.z) ROW(3, za.w)
            ROW(4, zb.x) ROW(5, zb.y) ROW(6, zb.z) ROW(7, zb.w)
            ROW(8, zc.x) ROW(9, zc.y) ROW(10, zc.z) ROW(11, zc.w)
            ROW(12, zd.x) ROW(13, zd.y) ROW(14, zd.z) ROW(15, zd.w)
#undef ROW
        }
        if (t + 1 < NT) STAGE_WRITE(cur ^ 1);
        __syncthreads();
        cur ^= 1;
    }
#undef STAGE_LOAD
#undef STAGE_WRITE

    float* pp = part + ((long)kc * 64 + r0) * N1 + n0 + c4;
#pragma unroll
    for (int r = 0; r < 16; r++)
        *(float4*)(pp + (long)r * N1) =
            make_float4(acc[r][0], acc[r][1], acc[r][2], acc[r][3]);
}

// ---------------- Kernel 3: reduce partials + bias + sigmoid ----------------
__global__ __launch_bounds__(256) void red1_kernel(const float* __restrict__ part,
        const float* __restrict__ b0v, float* __restrict__ z1, int ksplit) {
    __shared__ float4 red[256];
    const int tid = threadIdx.x;
    const int g = tid & 31, s = tid >> 5;
    const int gg = blockIdx.x * 32 + g;
    const int per = (ksplit + 7) >> 3;
    const int ks = s * per, ke = min(ksplit, ks + per);
    float4 a = make_float4(0.f, 0.f, 0.f, 0.f);
    for (int kc = ks; kc < ke; kc++) {
        float4 pv = *(const float4*)(part + ((long)kc * 8192 + gg) * 4);
        a.x += pv.x; a.y += pv.y; a.z += pv.z; a.w += pv.w;
    }
    red[tid] = a;
    __syncthreads();
    if (tid < 128) { float4 o = red[tid + 128]; red[tid].x += o.x; red[tid].y += o.y; red[tid].z += o.z; red[tid].w += o.w; }
    __syncthreads();
    if (tid < 64) { float4 o = red[tid + 64]; red[tid].x += o.x; red[tid].y += o.y; red[tid].z += o.z; red[tid].w += o.w; }
    __syncthreads();
    if (tid < 32) {
        float4 sum = red[tid];
        float4 o = red[tid + 32];
        sum.x += o.x; sum.y += o.y; sum.z += o.z; sum.w += o.w;
        const float4 bv = *(const float4*)(b0v + (gg & 127) * 4);
        float4 r;
        r.x = 1.f / (1.f + expf(-(sum.x + bv.x)));
        r.y = 1.f / (1.f + expf(-(sum.y + bv.y)));
        r.z = 1.f / (1.f + expf(-(sum.z + bv.z)));
        r.w = 1.f / (1.f + expf(-(sum.w + bv.w)));
        *(float4*)(z1 + gg * 4) = r;
    }
}

// ---------------- Kernel 4: GEMM2 + bias + sigmoid (in-block K-split) ----------------
__global__ __launch_bounds__(256) void gemm2_kernel(const float* __restrict__ z1,
        const float* __restrict__ w1, const float* __restrict__ b1v,
        float* __restrict__ z2) {
    __shared__ float red[256];
    const int m = blockIdx.x >> 2, nq = blockIdx.x & 3;
    const int tid = threadIdx.x;
    const int c = tid & 63, s = tid >> 6;
    const int n = nq * 64 + c;
    const float* zr = z1 + m * N1 + s * 128;
    const float* wr = w1 + (long)(s * 128) * N2 + n;
    float acc = 0.f;
#pragma unroll 16
    for (int k = 0; k < 128; k++) acc += zr[k] * wr[(long)k * N2];
    red[tid] = acc;
    __syncthreads();
    if (tid < 128) red[tid] += red[tid + 128];
    __syncthreads();
    if (tid < 64) {
        float sum = red[tid] + red[tid + 64] + b1v[n];
        z2[m * N2 + n] = 1.f / (1.f + expf(-sum));
    }
}

// ---------------- Kernel 5: GEMM3 + log_softmax ----------------
__global__ __launch_bounds__(64) void head_kernel(const float* __restrict__ z2,
        const float* __restrict__ w2, const float* __restrict__ b2v,
        float* __restrict__ out) {
    const int m = blockIdx.x;
    const int tid = threadIdx.x;
    __shared__ float logits[10];
    if (tid < 10) {
        float s = b2v[tid];
        const float* zr = z2 + m * N2;
#pragma unroll 8
        for (int k = 0; k < N2; k++) s += zr[k] * w2[k * 10 + tid];
        logits[tid] = s;
    }
    __syncthreads();
    if (tid == 0) {
        float mx = logits[0];
        for (int j = 1; j < 10; j++) mx = fmaxf(mx, logits[j]);
        float sum = 0.f;
        for (int j = 0; j < 10; j++) sum += expf(logits[j] - mx);
        const float lse = mx + logf(sum);
        for (int j = 0; j < 10; j++) out[m * 10 + j] = logits[j] - lse;
    }
}

extern "C" void kernel_launch(void* const* d_in, const int* in_sizes, int n_in,
                              void* d_out, int out_size, void* d_ws, size_t ws_size,
                              hipStream_t stream) {
    const float* x  = (const float*)d_in[0];
    const float* cw = (const float*)d_in[1];
    const float* cb = (const float*)d_in[2];
    const float* w0 = (const float*)d_in[3];
    const float* b0 = (const float*)d_in[4];
    const float* w1 = (const float*)d_in[5];
    const float* b1 = (const float*)d_in[6];
    const float* w2 = (const float*)d_in[7];
    const float* b2 = (const float*)d_in[8];

    // tiered K-split by workspace: 29520 = ksplit * KCH, KCH % 24 == 0
    const size_t fixed = (size_t)NPATH * SIGCH + 64 * N1 + 64 * N2;
    int ksplit = 82, kch = 360;
    if (ws_size >= (fixed + (size_t)246 * 64 * N1) * 4)      { ksplit = 246; kch = 120; }
    else if (ws_size >= (fixed + (size_t)123 * 64 * N1) * 4) { ksplit = 123; kch = 240; }

    float* ws   = (float*)d_ws;
    float* sigb = ws;                                // 256 x 7380 row-major
    float* part = sigb + (long)NPATH * SIGCH;        // ksplit*64*512
    float* z1   = part + (long)ksplit * 64 * N1;     // 64*512
    float* z2   = z1 + 64 * N1;                      // 64*256
    float* out  = (float*)d_out;

    sig_kernel<<<NPATH, 1024, 0, stream>>>(x, cw, cb, sigb);
    gemm1_kernel<<<dim3(2, ksplit), 256, 0, stream>>>(sigb, w0, part, kch);
    red1_kernel<<<256, 256, 0, stream>>>(part, b0, z1, ksplit);
    gemm2_kernel<<<256, 256, 0, stream>>>(z1, w1, b1, z2);
    head_kernel<<<64, 64, 0, stream>>>(z2, w2, b2, out);
}

// Round 13
// 114.948 us; speedup vs baseline: 1.4711x; 1.4711x over previous
//
#include <hip/hip_runtime.h>
#include <math.h>

#define TT 128
#define IN_CH 32
#define NPATH 256
#define SIGCH 7380
#define K1 29520
#define N1 512
#define N2 256

// ---------------- Kernel 1: conv + time-augment + depth-4 signature ----------------
// 512-thread block per path, 2 groups of 243 threads. Chen 2-way time-split:
// group g scans half [64g, 64g+64) independently; ONE merge. Group 1 dumps
// its sig into PADDED 48B-aligned LDS rows (sbN[row][12]) so the merge's
// 9-float slices vectorize to 2xb128+b32 instead of 9 scalar b32 reads.
// Output row-major sig[p][7380], coalesced.
__global__ __launch_bounds__(512, 1) void sig_kernel(const float* __restrict__ x,
        const float* __restrict__ cw, const float* __restrict__ cb,
        float* __restrict__ sig /*[256][7380]*/) {
    __shared__ float incT[9][132];
    __shared__ __align__(16) float sb1[12];
    __shared__ __align__(16) float sb2[9][12];
    __shared__ __align__(16) float sb3[81][12];
    __shared__ __align__(16) float sb4[729][12];
    const int p = blockIdx.x;
    const int b = p >> 2, oc = p & 3;
    const int tid = threadIdx.x;

    const float4 wv = *(const float4*)(cw + oc * 4);
    const float bias = cb[oc];
    const float* xb = x + (long)b * TT * IN_CH;

    for (int it = tid; it < TT * 8; it += 512) {
        const int t = it >> 3, ch = it & 7;
        const float4 xa = *(const float4*)(xb + t * IN_CH + ch * 4);
        float v = xa.x * wv.x + xa.y * wv.y + xa.z * wv.z + xa.w * wv.w + bias;
        if (t > 0) {
            const float4 xm = *(const float4*)(xb + (t - 1) * IN_CH + ch * 4);
            v -= xm.x * wv.x + xm.y * wv.y + xm.z * wv.z + xm.w * wv.w + bias;
        }
        incT[1 + ch][t] = v;
    }
    if (tid < TT) incT[0][tid] = tid ? (1.f / 127.f) : 0.f;
    __syncthreads();

    const int g = tid >> 8;              // group 0..1
    const int gtid = tid & 255;
    const bool act = gtid < 243;
    const int base3 = 3 * gtid;
    const int i1 = base3 / 81;
    const int i2 = (base3 / 9) % 9;
    const int i30 = base3 % 9;           // {0,3,6}
    const int lane = tid & 63;
    const int grow = min(lane, 8);

    float S4[3][9] = {};
    float s3[3] = {0.f, 0.f, 0.f};
    float s2 = 0.f, s1 = 0.f;

#define LD(R, T4) (*(const float4*)&incT[(R)][(T4)])
#define RL(XV, C) __int_as_float(__builtin_amdgcn_readlane(__float_as_int(XV), (C)))
#define STEP(GJ, E1, E2, F0, F1, F2) do { \
    const float t12 = (E1) * (E2); \
    const float s1d2 = s1 * (E2); \
    const float Ak = t12 * (1.f / 24.f) + s1d2 * (1.f / 6.f) + s2 * 0.5f; \
    const float Bk = t12 * (1.f / 6.f) + s1d2 * 0.5f + s2; \
    const float K0 = (F0) * Ak + s3[0]; \
    const float K1v = (F1) * Ak + s3[1]; \
    const float K2v = (F2) * Ak + s3[2]; \
    _Pragma("unroll") \
    for (int c = 0; c < 9; ++c) { \
        const float Ac = RL(GJ, c); \
        S4[0][c] += K0 * Ac; S4[1][c] += K1v * Ac; S4[2][c] += K2v * Ac; \
    } \
    s3[0] += Bk * (F0); s3[1] += Bk * (F1); s3[2] += Bk * (F2); \
    s2 += (E2) * (0.5f * (E1) + s1); \
    s1 += (E1); \
} while (0)

    if (act) {
        const int t0 = g * 64;
        float4 gA = LD(grow, t0), e1v = LD(i1, t0), e2v = LD(i2, t0);
        float4 f0v = LD(i30, t0), f1v = LD(i30 + 1, t0), f2v = LD(i30 + 2, t0);
        for (int j = 0; j < 16; ++j) {
            const int t4 = t0 + (((j + 1) & 15) << 2);    // last prefetch dummy
            const float4 ngA = LD(grow, t4);
            const float4 ne1 = LD(i1, t4), ne2 = LD(i2, t4);
            const float4 nf0 = LD(i30, t4), nf1 = LD(i30 + 1, t4), nf2 = LD(i30 + 2, t4);
            STEP(gA.x, e1v.x, e2v.x, f0v.x, f1v.x, f2v.x);
            STEP(gA.y, e1v.y, e2v.y, f0v.y, f1v.y, f2v.y);
            STEP(gA.z, e1v.z, e2v.z, f0v.z, f1v.z, f2v.z);
            STEP(gA.w, e1v.w, e2v.w, f0v.w, f1v.w, f2v.w);
            gA = ngA; e1v = ne1; e2v = ne2; f0v = nf0; f1v = nf1; f2v = nf2;
        }
    }
#undef STEP
#undef RL
#undef LD

    // group 1 -> padded LDS
    if (act && g == 1) {
        if (i2 == 0 && i30 == 0) sb1[i1] = s1;
        if (i30 == 0) sb2[i1][i2] = s2;
#pragma unroll
        for (int q = 0; q < 3; ++q) sb3[i1 * 9 + i2][i30 + q] = s3[q];
#pragma unroll
        for (int q = 0; q < 3; ++q)
#pragma unroll
            for (int c = 0; c < 9; ++c) sb4[base3 + q][c] = S4[q][c];
    }
    __syncthreads();

    // group 0 merges A (x) B and stores
    if (act && g == 0) {
        float S1B[9];
#pragma unroll
        for (int c = 0; c < 9; ++c) S1B[c] = sb1[c];
#pragma unroll
        for (int q = 0; q < 3; ++q) {
            const float* r2 = sb2[i30 + q];
            const float* r3 = sb3[i2 * 9 + i30 + q];
            const float* r4 = sb4[base3 + q];
#pragma unroll
            for (int c = 0; c < 9; ++c)
                S4[q][c] += s3[q] * S1B[c] + s2 * r2[c] + s1 * r3[c] + r4[c];
        }
#pragma unroll
        for (int q = 0; q < 3; ++q)
            s3[q] += s2 * S1B[i30 + q] + s1 * sb2[i2][i30 + q] + sb3[i1 * 9 + i2][i30 + q];
        s2 += s1 * S1B[i2] + sb2[i1][i2];
        s1 += S1B[i1];

        float* sp = sig + (long)p * SIGCH;
        if (i2 == 0 && i30 == 0) sp[i1] = s1;
        if (i30 == 0) sp[9 + base3 / 9] = s2;
        sp[90 + base3 + 0] = s3[0];
        sp[90 + base3 + 1] = s3[1];
        sp[90 + base3 + 2] = s3[2];
#pragma unroll
        for (int q = 0; q < 3; q++)
#pragma unroll
            for (int l = 0; l < 9; l++)
                sp[819 + (base3 + q) * 9 + l] = S4[q][l];
    }
}

// ---------------- Kernel 2: GEMM1 partials ----------------
// Block = 64 rows x 128 cols, 256 thr / 4 waves; wave = 16 rows x 128 cols
// (2 cols/lane, acc[16][2]=32 VGPR). Grid = 4 n-quarters x 123 k-chunks =
// 492 blocks (~2/CU, plus low VGPR/LDS -> 4-6 waves/SIMD TLP). z read from
// row-major sig via wave-uniform s_load batches (16 dwordx4 per 4-k half,
// amortized over 256 FMA-cyc; TLP covers the lgkm drain). w tile [8][128]
// LDS dbuf (reg-staged f4, 1 barrier/tile); per k one conflict-free b64
// read/lane vs 32 FMA -> LDS ratio 0.375, VALU-bound.
__global__ __launch_bounds__(256) void gemm1_kernel(const float* __restrict__ zsig,
        const float* __restrict__ w0, float* __restrict__ part, int KCH) {
    __shared__ float wt[2][8][128];
    const int nq = blockIdx.x;            // 0..3
    const int kc = blockIdx.y;
    const int n0 = nq * 128, k0 = kc * KCH;
    const int tid = threadIdx.x;
    const int lane = tid & 63;
    const int wvid = __builtin_amdgcn_readfirstlane(tid >> 6);  // 0..3
    const int r0 = wvid * 16;
    const int c2 = lane * 2;
    const int sk = tid >> 5, sc = (tid & 31) * 4;  // staging: 8 k-rows x 32 quads

    float4 stg = *(const float4*)(w0 + (long)(k0 + sk) * N1 + n0 + sc);

    float acc[16][2] = {};
    const int NT = KCH / 8;
    int cur = 0;

    for (int t = 0; t < NT; ++t) {
        *(float4*)&wt[cur][sk][sc] = stg;
        __syncthreads();
        if (t + 1 < NT)
            stg = *(const float4*)(w0 + (long)(k0 + (t + 1) * 8 + sk) * N1 + n0 + sc);
        const int kk = k0 + t * 8;
#pragma unroll
        for (int h = 0; h < 2; ++h) {
            float4 zf[16];                 // wave-uniform -> SGPRs (s_load)
#pragma unroll
            for (int r = 0; r < 16; ++r)
                zf[r] = *(const float4*)(zsig + (long)(r0 + r) * K1 + kk + h * 4);
#pragma unroll
            for (int k = 0; k < 4; ++k) {
                const float2 wf = *(const float2*)&wt[cur][h * 4 + k][c2];
#pragma unroll
                for (int r = 0; r < 16; ++r) {
                    const float zv = (k == 0) ? zf[r].x : (k == 1) ? zf[r].y
                                   : (k == 2) ? zf[r].z : zf[r].w;
                    acc[r][0] += zv * wf.x;
                    acc[r][1] += zv * wf.y;
                }
            }
        }
        __syncthreads();
        cur ^= 1;
    }

    float* pp = part + ((long)kc * 64 + r0) * N1 + n0 + c2;
#pragma unroll
    for (int r = 0; r < 16; r++)
        *(float2*)(pp + (long)r * N1) = make_float2(acc[r][0], acc[r][1]);
}

// ---------------- Kernel 3: reduce partials + bias + sigmoid ----------------
__global__ __launch_bounds__(256) void red1_kernel(const float* __restrict__ part,
        const float* __restrict__ b0v, float* __restrict__ z1, int ksplit) {
    __shared__ float4 red[256];
    const int tid = threadIdx.x;
    const int g = tid & 31, s = tid >> 5;
    const int gg = blockIdx.x * 32 + g;
    const int per = (ksplit + 7) >> 3;
    const int ks = s * per, ke = min(ksplit, ks + per);
    float4 a = make_float4(0.f, 0.f, 0.f, 0.f);
    for (int kc = ks; kc < ke; kc++) {
        float4 pv = *(const float4*)(part + ((long)kc * 8192 + gg) * 4);
        a.x += pv.x; a.y += pv.y; a.z += pv.z; a.w += pv.w;
    }
    red[tid] = a;
    __syncthreads();
    if (tid < 128) { float4 o = red[tid + 128]; red[tid].x += o.x; red[tid].y += o.y; red[tid].z += o.z; red[tid].w += o.w; }
    __syncthreads();
    if (tid < 64) { float4 o = red[tid + 64]; red[tid].x += o.x; red[tid].y += o.y; red[tid].z += o.z; red[tid].w += o.w; }
    __syncthreads();
    if (tid < 32) {
        float4 sum = red[tid];
        float4 o = red[tid + 32];
        sum.x += o.x; sum.y += o.y; sum.z += o.z; sum.w += o.w;
        const float4 bv = *(const float4*)(b0v + (gg & 127) * 4);
        float4 r;
        r.x = 1.f / (1.f + expf(-(sum.x + bv.x)));
        r.y = 1.f / (1.f + expf(-(sum.y + bv.y)));
        r.z = 1.f / (1.f + expf(-(sum.z + bv.z)));
        r.w = 1.f / (1.f + expf(-(sum.w + bv.w)));
        *(float4*)(z1 + gg * 4) = r;
    }
}

// ---------------- Kernel 4: GEMM2 + bias + sigmoid (in-block K-split) ----------------
__global__ __launch_bounds__(256) void gemm2_kernel(const float* __restrict__ z1,
        const float* __restrict__ w1, const float* __restrict__ b1v,
        float* __restrict__ z2) {
    __shared__ float red[256];
    const int m = blockIdx.x >> 2, nq = blockIdx.x & 3;
    const int tid = threadIdx.x;
    const int c = tid & 63, s = tid >> 6;
    const int n = nq * 64 + c;
    const float* zr = z1 + m * N1 + s * 128;
    const float* wr = w1 + (long)(s * 128) * N2 + n;
    float acc = 0.f;
#pragma unroll 16
    for (int k = 0; k < 128; k++) acc += zr[k] * wr[(long)k * N2];
    red[tid] = acc;
    __syncthreads();
    if (tid < 128) red[tid] += red[tid + 128];
    __syncthreads();
    if (tid < 64) {
        float sum = red[tid] + red[tid + 64] + b1v[n];
        z2[m * N2 + n] = 1.f / (1.f + expf(-sum));
    }
}

// ---------------- Kernel 5: GEMM3 + log_softmax ----------------
__global__ __launch_bounds__(64) void head_kernel(const float* __restrict__ z2,
        const float* __restrict__ w2, const float* __restrict__ b2v,
        float* __restrict__ out) {
    const int m = blockIdx.x;
    const int tid = threadIdx.x;
    __shared__ float logits[10];
    if (tid < 10) {
        float s = b2v[tid];
        const float* zr = z2 + m * N2;
#pragma unroll 8
        for (int k = 0; k < N2; k++) s += zr[k] * w2[k * 10 + tid];
        logits[tid] = s;
    }
    __syncthreads();
    if (tid == 0) {
        float mx = logits[0];
        for (int j = 1; j < 10; j++) mx = fmaxf(mx, logits[j]);
        float sum = 0.f;
        for (int j = 0; j < 10; j++) sum += expf(logits[j] - mx);
        const float lse = mx + logf(sum);
        for (int j = 0; j < 10; j++) out[m * 10 + j] = logits[j] - lse;
    }
}

extern "C" void kernel_launch(void* const* d_in, const int* in_sizes, int n_in,
                              void* d_out, int out_size, void* d_ws, size_t ws_size,
                              hipStream_t stream) {
    const float* x  = (const float*)d_in[0];
    const float* cw = (const float*)d_in[1];
    const float* cb = (const float*)d_in[2];
    const float* w0 = (const float*)d_in[3];
    const float* b0 = (const float*)d_in[4];
    const float* w1 = (const float*)d_in[5];
    const float* b1 = (const float*)d_in[6];
    const float* w2 = (const float*)d_in[7];
    const float* b2 = (const float*)d_in[8];

    // tiered K-split by workspace: 29520 = ksplit * KCH, KCH % 8 == 0
    const size_t fixed = (size_t)NPATH * SIGCH + 64 * N1 + 64 * N2;
    int ksplit = 41, kch = 720;
    if (ws_size >= (fixed + (size_t)123 * 64 * N1) * 4)      { ksplit = 123; kch = 240; }
    else if (ws_size >= (fixed + (size_t)82 * 64 * N1) * 4)  { ksplit = 82;  kch = 360; }

    float* ws   = (float*)d_ws;
    float* sigb = ws;                                // 256 x 7380 row-major
    float* part = sigb + (long)NPATH * SIGCH;        // ksplit*64*512
    float* z1   = part + (long)ksplit * 64 * N1;     // 64*512
    float* z2   = z1 + 64 * N1;                      // 64*256
    float* out  = (float*)d_out;

    sig_kernel<<<NPATH, 512, 0, stream>>>(x, cw, cb, sigb);
    gemm1_kernel<<<dim3(4, ksplit), 256, 0, stream>>>(sigb, w0, part, kch);
    red1_kernel<<<256, 256, 0, stream>>>(part, b0, z1, ksplit);
    gemm2_kernel<<<256, 256, 0, stream>>>(z1, w1, b1, z2);
    head_kernel<<<64, 64, 0, stream>>>(z2, w2, b2, out);
}

// Round 14
// 89.844 us; speedup vs baseline: 1.8822x; 1.2794x over previous
//
#include <hip/hip_runtime.h>
#include <math.h>

#define TT 128
#define IN_CH 32
#define NPATH 256
#define SIGCH 7380
#define K1 29520
#define N1 512
#define N2 256
#define BKG 8

// ---------------- Kernel 1: conv + time-augment + depth-4 signature ----------------
// (unchanged from r13; candidate bottleneck — measure this round)
__global__ __launch_bounds__(512, 1) void sig_kernel(const float* __restrict__ x,
        const float* __restrict__ cw, const float* __restrict__ cb,
        float* __restrict__ sig /*[256][7380]*/) {
    __shared__ float incT[9][132];
    __shared__ __align__(16) float sb1[12];
    __shared__ __align__(16) float sb2[9][12];
    __shared__ __align__(16) float sb3[81][12];
    __shared__ __align__(16) float sb4[729][12];
    const int p = blockIdx.x;
    const int b = p >> 2, oc = p & 3;
    const int tid = threadIdx.x;

    const float4 wv = *(const float4*)(cw + oc * 4);
    const float bias = cb[oc];
    const float* xb = x + (long)b * TT * IN_CH;

    for (int it = tid; it < TT * 8; it += 512) {
        const int t = it >> 3, ch = it & 7;
        const float4 xa = *(const float4*)(xb + t * IN_CH + ch * 4);
        float v = xa.x * wv.x + xa.y * wv.y + xa.z * wv.z + xa.w * wv.w + bias;
        if (t > 0) {
            const float4 xm = *(const float4*)(xb + (t - 1) * IN_CH + ch * 4);
            v -= xm.x * wv.x + xm.y * wv.y + xm.z * wv.z + xm.w * wv.w + bias;
        }
        incT[1 + ch][t] = v;
    }
    if (tid < TT) incT[0][tid] = tid ? (1.f / 127.f) : 0.f;
    __syncthreads();

    const int g = tid >> 8;
    const int gtid = tid & 255;
    const bool act = gtid < 243;
    const int base3 = 3 * gtid;
    const int i1 = base3 / 81;
    const int i2 = (base3 / 9) % 9;
    const int i30 = base3 % 9;
    const int lane = tid & 63;
    const int grow = min(lane, 8);

    float S4[3][9] = {};
    float s3[3] = {0.f, 0.f, 0.f};
    float s2 = 0.f, s1 = 0.f;

#define LD(R, T4) (*(const float4*)&incT[(R)][(T4)])
#define RL(XV, C) __int_as_float(__builtin_amdgcn_readlane(__float_as_int(XV), (C)))
#define STEP(GJ, E1, E2, F0, F1, F2) do { \
    const float t12 = (E1) * (E2); \
    const float s1d2 = s1 * (E2); \
    const float Ak = t12 * (1.f / 24.f) + s1d2 * (1.f / 6.f) + s2 * 0.5f; \
    const float Bk = t12 * (1.f / 6.f) + s1d2 * 0.5f + s2; \
    const float K0 = (F0) * Ak + s3[0]; \
    const float K1v = (F1) * Ak + s3[1]; \
    const float K2v = (F2) * Ak + s3[2]; \
    _Pragma("unroll") \
    for (int c = 0; c < 9; ++c) { \
        const float Ac = RL(GJ, c); \
        S4[0][c] += K0 * Ac; S4[1][c] += K1v * Ac; S4[2][c] += K2v * Ac; \
    } \
    s3[0] += Bk * (F0); s3[1] += Bk * (F1); s3[2] += Bk * (F2); \
    s2 += (E2) * (0.5f * (E1) + s1); \
    s1 += (E1); \
} while (0)

    if (act) {
        const int t0 = g * 64;
        float4 gA = LD(grow, t0), e1v = LD(i1, t0), e2v = LD(i2, t0);
        float4 f0v = LD(i30, t0), f1v = LD(i30 + 1, t0), f2v = LD(i30 + 2, t0);
        for (int j = 0; j < 16; ++j) {
            const int t4 = t0 + (((j + 1) & 15) << 2);
            const float4 ngA = LD(grow, t4);
            const float4 ne1 = LD(i1, t4), ne2 = LD(i2, t4);
            const float4 nf0 = LD(i30, t4), nf1 = LD(i30 + 1, t4), nf2 = LD(i30 + 2, t4);
            STEP(gA.x, e1v.x, e2v.x, f0v.x, f1v.x, f2v.x);
            STEP(gA.y, e1v.y, e2v.y, f0v.y, f1v.y, f2v.y);
            STEP(gA.z, e1v.z, e2v.z, f0v.z, f1v.z, f2v.z);
            STEP(gA.w, e1v.w, e2v.w, f0v.w, f1v.w, f2v.w);
            gA = ngA; e1v = ne1; e2v = ne2; f0v = nf0; f1v = nf1; f2v = nf2;
        }
    }
#undef STEP
#undef RL
#undef LD

    if (act && g == 1) {
        if (i2 == 0 && i30 == 0) sb1[i1] = s1;
        if (i30 == 0) sb2[i1][i2] = s2;
#pragma unroll
        for (int q = 0; q < 3; ++q) sb3[i1 * 9 + i2][i30 + q] = s3[q];
#pragma unroll
        for (int q = 0; q < 3; ++q)
#pragma unroll
            for (int c = 0; c < 9; ++c) sb4[base3 + q][c] = S4[q][c];
    }
    __syncthreads();

    if (act && g == 0) {
        float S1B[9];
#pragma unroll
        for (int c = 0; c < 9; ++c) S1B[c] = sb1[c];
#pragma unroll
        for (int q = 0; q < 3; ++q) {
            const float* r2 = sb2[i30 + q];
            const float* r3 = sb3[i2 * 9 + i30 + q];
            const float* r4 = sb4[base3 + q];
#pragma unroll
            for (int c = 0; c < 9; ++c)
                S4[q][c] += s3[q] * S1B[c] + s2 * r2[c] + s1 * r3[c] + r4[c];
        }
#pragma unroll
        for (int q = 0; q < 3; ++q)
            s3[q] += s2 * S1B[i30 + q] + s1 * sb2[i2][i30 + q] + sb3[i1 * 9 + i2][i30 + q];
        s2 += s1 * S1B[i2] + sb2[i1][i2];
        s1 += S1B[i1];

        float* sp = sig + (long)p * SIGCH;
        if (i2 == 0 && i30 == 0) sp[i1] = s1;
        if (i30 == 0) sp[9 + base3 / 9] = s2;
        sp[90 + base3 + 0] = s3[0];
        sp[90 + base3 + 1] = s3[1];
        sp[90 + base3 + 2] = s3[2];
#pragma unroll
        for (int q = 0; q < 3; q++)
#pragma unroll
            for (int l = 0; l < 9; l++)
                sp[819 + (base3 + q) * 9 + l] = S4[q][l];
    }
}

// ---------------- Kernel 2: GEMM1 partials (pure-LDS, no s_load, no spills) ----------------
// 512 thr / 8 waves, full 64x512 tile, grid = pure k-split (246 blocks).
// Wave = 8 rows x 512 cols; lane owns cols {4L..4L+3} u {256+4L..+3} (acc 64).
// Per k: 2 uniform-address b128 (z rows, broadcast) + 2 per-lane contiguous
// b128 (w, canonical conflict-free) feeding 64 FMA -> LDS:VALU ~1.1.
// Staging per BK=8 tile: w = 2 float4/thread regs (small, no spill) -> LDS;
// z = 1 float/thread -> transposed zt[8][68] (pad 68: <=2-way write aliasing).
__global__ __launch_bounds__(512) void gemm1_kernel(const float* __restrict__ zsig,
        const float* __restrict__ w0, float* __restrict__ part, int KCH) {
    __shared__ float wt[2][BKG][512];
    __shared__ float zt[2][BKG][68];
    const int kc = blockIdx.x;
    const int k0 = kc * KCH;
    const int tid = threadIdx.x;
    const int lane = tid & 63;
    const int wvid = __builtin_amdgcn_readfirstlane(tid >> 6);  // 0..7
    const int r0 = wvid * 8;
    const int c4a = lane * 4, c4b = 256 + lane * 4;
    const int swk = tid >> 6, swc = lane * 8;     // w staging: row swk, 8 floats
    const int szr = tid >> 3, szj = tid & 7;      // z staging: sig[szr][k+szj]

    float4 wA = *(const float4*)(w0 + (long)(k0 + swk) * N1 + swc);
    float4 wB = *(const float4*)(w0 + (long)(k0 + swk) * N1 + swc + 4);
    float zs = zsig[(long)szr * K1 + k0 + szj];

    *(float4*)&wt[0][swk][swc] = wA;
    *(float4*)&wt[0][swk][swc + 4] = wB;
    zt[0][szj][szr] = zs;
    __syncthreads();

    float acc[8][8] = {};
    const int NT = KCH / BKG;
    int cur = 0;

    for (int t = 0; t < NT; ++t) {
        if (t + 1 < NT) {
            const long kn = (long)(k0 + (t + 1) * BKG);
            wA = *(const float4*)(w0 + (kn + swk) * N1 + swc);
            wB = *(const float4*)(w0 + (kn + swk) * N1 + swc + 4);
            zs = zsig[(long)szr * K1 + kn + szj];
        }
#pragma unroll
        for (int k = 0; k < BKG; ++k) {
            const float4 za = *(const float4*)&zt[cur][k][r0];        // uniform
            const float4 zb = *(const float4*)&zt[cur][k][r0 + 4];    // uniform
            const float4 wa = *(const float4*)&wt[cur][k][c4a];       // tiled
            const float4 wb = *(const float4*)&wt[cur][k][c4b];       // tiled
#define ROW(R, ZV) \
            acc[R][0] += (ZV) * wa.x; acc[R][1] += (ZV) * wa.y; \
            acc[R][2] += (ZV) * wa.z; acc[R][3] += (ZV) * wa.w; \
            acc[R][4] += (ZV) * wb.x; acc[R][5] += (ZV) * wb.y; \
            acc[R][6] += (ZV) * wb.z; acc[R][7] += (ZV) * wb.w;
            ROW(0, za.x) ROW(1, za.y) ROW(2, za.z) ROW(3, za.w)
            ROW(4, zb.x) ROW(5, zb.y) ROW(6, zb.z) ROW(7, zb.w)
#undef ROW
        }
        if (t + 1 < NT) {
            *(float4*)&wt[cur ^ 1][swk][swc] = wA;
            *(float4*)&wt[cur ^ 1][swk][swc + 4] = wB;
            zt[cur ^ 1][szj][szr] = zs;
        }
        __syncthreads();
        cur ^= 1;
    }

    float* pp = part + ((long)kc * 64 + r0) * N1;
#pragma unroll
    for (int r = 0; r < 8; r++) {
        *(float4*)(pp + (long)r * N1 + c4a) =
            make_float4(acc[r][0], acc[r][1], acc[r][2], acc[r][3]);
        *(float4*)(pp + (long)r * N1 + c4b) =
            make_float4(acc[r][4], acc[r][5], acc[r][6], acc[r][7]);
    }
}

// ---------------- Kernel 3: reduce partials + bias + sigmoid ----------------
__global__ __launch_bounds__(256) void red1_kernel(const float* __restrict__ part,
        const float* __restrict__ b0v, float* __restrict__ z1, int ksplit) {
    __shared__ float4 red[256];
    const int tid = threadIdx.x;
    const int g = tid & 31, s = tid >> 5;
    const int gg = blockIdx.x * 32 + g;
    const int per = (ksplit + 7) >> 3;
    const int ks = s * per, ke = min(ksplit, ks + per);
    float4 a = make_float4(0.f, 0.f, 0.f, 0.f);
    for (int kc = ks; kc < ke; kc++) {
        float4 pv = *(const float4*)(part + ((long)kc * 8192 + gg) * 4);
        a.x += pv.x; a.y += pv.y; a.z += pv.z; a.w += pv.w;
    }
    red[tid] = a;
    __syncthreads();
    if (tid < 128) { float4 o = red[tid + 128]; red[tid].x += o.x; red[tid].y += o.y; red[tid].z += o.z; red[tid].w += o.w; }
    __syncthreads();
    if (tid < 64) { float4 o = red[tid + 64]; red[tid].x += o.x; red[tid].y += o.y; red[tid].z += o.z; red[tid].w += o.w; }
    __syncthreads();
    if (tid < 32) {
        float4 sum = red[tid];
        float4 o = red[tid + 32];
        sum.x += o.x; sum.y += o.y; sum.z += o.z; sum.w += o.w;
        const float4 bv = *(const float4*)(b0v + (gg & 127) * 4);
        float4 r;
        r.x = 1.f / (1.f + expf(-(sum.x + bv.x)));
        r.y = 1.f / (1.f + expf(-(sum.y + bv.y)));
        r.z = 1.f / (1.f + expf(-(sum.z + bv.z)));
        r.w = 1.f / (1.f + expf(-(sum.w + bv.w)));
        *(float4*)(z1 + gg * 4) = r;
    }
}

// ---------------- Kernel 4: fused GEMM2+sigmoid+GEMM3+log_softmax ----------------
__global__ __launch_bounds__(256) void tail_kernel(const float* __restrict__ z1,
        const float* __restrict__ w1, const float* __restrict__ b1v,
        const float* __restrict__ w2, const float* __restrict__ b2v,
        float* __restrict__ out) {
    __shared__ float z2row[N2];
    __shared__ float red[160];
    __shared__ float logits[10];
    const int m = blockIdx.x;
    const int tid = threadIdx.x;
    const float* zr = z1 + m * N1;
    float acc = b1v[tid];
#pragma unroll 8
    for (int k = 0; k < N1; k++) acc += zr[k] * w1[(long)k * N2 + tid];
    z2row[tid] = 1.f / (1.f + expf(-acc));
    __syncthreads();
    if (tid < 160) {
        const int j = tid >> 4, s = tid & 15;
        float p = 0.f;
#pragma unroll
        for (int kk = 0; kk < 16; kk++) {
            const int k = s * 16 + kk;
            p += z2row[k] * w2[k * 10 + j];
        }
        red[tid] = p;
    }
    __syncthreads();
    if (tid < 10) {
        float lg = b2v[tid];
#pragma unroll
        for (int s = 0; s < 16; s++) lg += red[tid * 16 + s];
        logits[tid] = lg;
    }
    __syncthreads();
    if (tid == 0) {
        float mx = logits[0];
        for (int j = 1; j < 10; j++) mx = fmaxf(mx, logits[j]);
        float sum = 0.f;
        for (int j = 0; j < 10; j++) sum += expf(logits[j] - mx);
        const float lse = mx + logf(sum);
        for (int j = 0; j < 10; j++) out[m * 10 + j] = logits[j] - lse;
    }
}

extern "C" void kernel_launch(void* const* d_in, const int* in_sizes, int n_in,
                              void* d_out, int out_size, void* d_ws, size_t ws_size,
                              hipStream_t stream) {
    const float* x  = (const float*)d_in[0];
    const float* cw = (const float*)d_in[1];
    const float* cb = (const float*)d_in[2];
    const float* w0 = (const float*)d_in[3];
    const float* b0 = (const float*)d_in[4];
    const float* w1 = (const float*)d_in[5];
    const float* b1 = (const float*)d_in[6];
    const float* w2 = (const float*)d_in[7];
    const float* b2 = (const float*)d_in[8];

    // tiered K-split by workspace: 29520 = ksplit * KCH, KCH % 8 == 0
    const size_t fixed = (size_t)NPATH * SIGCH + 64 * N1 + 64 * N2;
    int ksplit = 82, kch = 360;
    if (ws_size >= (fixed + (size_t)246 * 64 * N1) * 4)      { ksplit = 246; kch = 120; }
    else if (ws_size >= (fixed + (size_t)123 * 64 * N1) * 4) { ksplit = 123; kch = 240; }

    float* ws   = (float*)d_ws;
    float* sigb = ws;                                // 256 x 7380 row-major
    float* part = sigb + (long)NPATH * SIGCH;        // ksplit*64*512
    float* z1   = part + (long)ksplit * 64 * N1;     // 64*512
    float* out  = (float*)d_out;

    sig_kernel<<<NPATH, 512, 0, stream>>>(x, cw, cb, sigb);
    gemm1_kernel<<<ksplit, 512, 0, stream>>>(sigb, w0, part, kch);
    red1_kernel<<<256, 256, 0, stream>>>(part, b0, z1, ksplit);
    tail_kernel<<<64, 256, 0, stream>>>(z1, w1, b1, w2, b2, out);
}